// Round 2
// baseline (26402.271 us; speedup 1.0000x reference)
//
#include <hip/hip_runtime.h>
#include <hip/hip_fp16.h>

constexpr int kB = 128;
constexpr int kN = 1000;
constexpr int kE = 128;
constexpr int kH = 8;
constexpr float kScale = 0.25f;  // 1/sqrt(d), d = 16

typedef _Float16 h2v __attribute__((ext_vector_type(2)));
__device__ __forceinline__ float h2fma2(unsigned a, unsigned b, float s) {
  // v_dot2_f32_f16: s += a.lo*b.lo + a.hi*b.hi
  return __builtin_amdgcn_fdot2(__builtin_bit_cast(h2v, a),
                                __builtin_bit_cast(h2v, b), s, false);
}
__device__ __forceinline__ float dotu4(uint4 a, uint4 b, float s) {
  s = h2fma2(a.x, b.x, s);
  s = h2fma2(a.y, b.y, s);
  s = h2fma2(a.z, b.z, s);
  s = h2fma2(a.w, b.w, s);
  return s;
}

// online-softmax / argmax combine. Tie on value -> smaller node index wins
// (matches jnp.argmax first-occurrence semantics).
__device__ __forceinline__ void combine(float& m, float& s, int& a,
                                        float mo, float so, int ao) {
  bool take = (mo > m) || (mo == m && ao < a);
  float mw = take ? mo : m;
  float ml = take ? m : mo;
  float sw = take ? so : s;
  float sl = take ? s : so;
  s = sw + sl * __expf(ml - mw);
  m = mw;
  a = take ? ao : a;
}

// ---------------------------------------------------------------------------
// Kernel A: qkv = node_embeddings @ Wqkv + bqkv, split to k/v/logit_k, f16.
// ---------------------------------------------------------------------------
__global__ __launch_bounds__(384) void qkv_kernel(
    const float* __restrict__ ne, const float* __restrict__ Wqkv,
    const float* __restrict__ bqkv, __half* __restrict__ kh,
    __half* __restrict__ vh, __half* __restrict__ lkh) {
  __shared__ float rows[16 * kE];
  int b = blockIdx.x;
  int n0 = blockIdx.y * 16;
  int ntile = min(16, kN - n0);
  int tid = threadIdx.x;

  for (int idx = tid; idx < ntile * kE; idx += 384)
    rows[idx] = ne[(b * kN + n0) * kE + idx];
  __syncthreads();

  int j = tid;  // 0..383
  float acc[16];
#pragma unroll
  for (int r = 0; r < 16; ++r) acc[r] = 0.f;
  for (int i = 0; i < kE; ++i) {
    float w = Wqkv[i * (3 * kE) + j];
#pragma unroll
    for (int r = 0; r < 16; ++r) acc[r] += rows[r * kE + i] * w;
  }
  float bias = bqkv[j];
  __half* dst;
  int col;
  if (j < kE) { dst = kh; col = j; }
  else if (j < 2 * kE) { dst = vh; col = j - kE; }
  else { dst = lkh; col = j - 2 * kE; }
  for (int r = 0; r < ntile; ++r)
    dst[(b * kN + n0 + r) * kE + col] = __float2half(acc[r] + bias);
}

// ---------------------------------------------------------------------------
// Kernel B: qbase[b] = ge@Wfix + bfix + first@Wstep_top + bstep  (fp32)
// ---------------------------------------------------------------------------
__global__ __launch_bounds__(128) void qbase_kernel(
    const float* __restrict__ ne, const float* __restrict__ ge,
    const float* __restrict__ Wfix, const float* __restrict__ bfix,
    const float* __restrict__ Wstep, const float* __restrict__ bstep,
    float* __restrict__ qbase) {
  __shared__ float g[kE], f[kE];
  int b = blockIdx.x, e = threadIdx.x;
  g[e] = ge[b * kE + e];
  f[e] = ne[b * kN * kE + e];  // node 0
  __syncthreads();
  float acc = bfix[e] + bstep[e];
  for (int i = 0; i < kE; ++i)
    acc += g[i] * Wfix[i * kE + e] + f[i] * Wstep[i * kE + e];
  qbase[b * kE + e] = acc;
}

// ---------------------------------------------------------------------------
// Kernel C: 999-step rollout, one 1024-thread block per batch element.
// Remaining-node compaction: rem[0..R) holds live node ids, pos[] inverse.
// ---------------------------------------------------------------------------
__global__ __launch_bounds__(1024) void rollout_kernel(
    const float* __restrict__ ne, const float* __restrict__ Wstep,
    const float* __restrict__ Wmlp, const float* __restrict__ bmlp,
    const __half* __restrict__ kh, const __half* __restrict__ vh,
    const __half* __restrict__ lkh, const float* __restrict__ qbase,
    float* __restrict__ out) {
  __shared__ float p[kN * kH];     // exp(scores), indexed [j*8+h], 32 KB
  __shared__ int rem[kN];          // live node ids
  __shared__ int pos[kN];          // node id -> position in rem
  __shared__ float parts[16 * kE]; // ctx wave partials, 8 KB
  __shared__ float qb[kE];
  __shared__ float bm[kE];
  __shared__ float ctx[kE];
  __shared__ __align__(16) __half qh[kE];
  __shared__ __align__(16) __half xh[kE];
  __shared__ float redSum[16][kH];
  __shared__ float redM[16], redS[16];
  __shared__ int redI[16];
  __shared__ int cur_s, R_s;
  __shared__ float total_s;

  int b = blockIdx.x;
  int tid = threadIdx.x;
  int lane = tid & 63;
  int wave = tid >> 6;
  int e8 = tid >> 3;  // matvec: element
  int c8 = tid & 7;   // matvec: i-chunk (16 i's each)

  const float* Wbot = Wstep + kE * kE;  // rows for `last`
  const float* neb = ne + (size_t)b * kN * kE;
  const __half* khb = kh + (size_t)b * kN * kE;
  const __half* vhb = vh + (size_t)b * kN * kE;
  const __half* lkb = lkh + (size_t)b * kN * kE;

  for (int i = tid; i < kN - 1; i += 1024) { rem[i] = i + 1; pos[i + 1] = i; }
  if (tid < kE) { qb[tid] = qbase[b * kE + tid]; bm[tid] = bmlp[tid]; }
  if (tid == 0) { cur_s = 0; R_s = kN - 1; total_s = 0.f; }
  __syncthreads();

  for (int step = 0; step < kN - 1; ++step) {
    int R = R_s;
    int cur = cur_s;

    // ---- q = qb + ne[cur] @ Wbot; thread (e8,c8), shuffle-reduce over c8
    {
      const float4* row4 = (const float4*)(neb + (size_t)cur * kE) + c8 * 4;
      const float* w = Wbot + (c8 * 16) * kE + e8;
      float acc = 0.f;
#pragma unroll
      for (int q = 0; q < 4; ++q) {
        float4 r = row4[q];
        acc += r.x * w[(4 * q + 0) * kE] + r.y * w[(4 * q + 1) * kE] +
               r.z * w[(4 * q + 2) * kE] + r.w * w[(4 * q + 3) * kE];
      }
      acc += __shfl_xor(acc, 1);
      acc += __shfl_xor(acc, 2);
      acc += __shfl_xor(acc, 4);
      if (c8 == 0) qh[e8] = __float2half(qb[e8] + acc);
    }
    __syncthreads();  // B1: qh ready

    // ---- scores + exp; one live node per thread
    {
      float hv[kH];
#pragma unroll
      for (int h = 0; h < kH; ++h) hv[h] = 0.f;
      if (tid < R) {
        int node = rem[tid];
        const uint4* krow = (const uint4*)(khb + (size_t)node * kE);
        const uint4* q4 = (const uint4*)qh;
#pragma unroll
        for (int h = 0; h < kH; ++h) {
          float s = dotu4(krow[2 * h], q4[2 * h], 0.f);
          s = dotu4(krow[2 * h + 1], q4[2 * h + 1], s);
          hv[h] = __expf(s * kScale);  // scores tiny: no max-subtract needed
        }
        float* prow = p + tid * kH;
        ((float4*)prow)[0] = make_float4(hv[0], hv[1], hv[2], hv[3]);
        ((float4*)prow)[1] = make_float4(hv[4], hv[5], hv[6], hv[7]);
      }
#pragma unroll
      for (int h = 0; h < kH; ++h) {
        float v = hv[h];
#pragma unroll
        for (int off = 32; off; off >>= 1) v += __shfl_xor(v, off);
        if (lane == 0) redSum[wave][h] = v;
      }
    }
    __syncthreads();  // B2: p, redSum ready

    // ---- ctx wave-partials: wave w strides live list; lane = half2 index
    {
      int h = lane >> 3;  // head of element pair (2*lane, 2*lane+1)
      float a0 = 0.f, a1 = 0.f;
      for (int j = wave; j < R; j += 16) {
        int node = rem[j];
        float w_ = p[j * kH + h];
        float2 vf =
            __half22float2(((const __half2*)(vhb + (size_t)node * kE))[lane]);
        a0 += w_ * vf.x;
        a1 += w_ * vf.y;
      }
      ((float2*)(parts + wave * kE))[lane] = make_float2(a0, a1);
    }
    __syncthreads();  // B3: parts ready

    // ---- ctx combine + softmax normalize (denominator folded in here)
    if (tid < kE) {
      int h = tid >> 4;
      float den = 0.f, s = 0.f;
#pragma unroll
      for (int w = 0; w < 16; ++w) {
        den += redSum[w][h];
        s += parts[w * kE + tid];
      }
      ctx[tid] = s / den;
    }
    __syncthreads();  // B4: ctx ready

    // ---- x = bm + ctx @ Wmlp
    {
      const float* w = Wmlp + (c8 * 16) * kE + e8;
      float acc = 0.f;
#pragma unroll
      for (int i = 0; i < 16; ++i) acc += ctx[c8 * 16 + i] * w[i * kE];
      acc += __shfl_xor(acc, 1);
      acc += __shfl_xor(acc, 2);
      acc += __shfl_xor(acc, 4);
      if (c8 == 0) xh[e8] = __float2half(bm[e8] + acc);
    }
    __syncthreads();  // B5: xh ready

    // ---- logits + online log-softmax + argmax; one live node per thread
    float m = -1e30f, ssum = 0.f;
    int arg = 0x7fffffff;
    if (tid < R) {
      int node = rem[tid];
      const uint4* lrow = (const uint4*)(lkb + (size_t)node * kE);
      const uint4* x4 = (const uint4*)xh;
      float s = 0.f;
#pragma unroll
      for (int j = 0; j < 16; ++j) s = dotu4(lrow[j], x4[j], s);
      m = tanhf(s * kScale) * 10.f;
      ssum = 1.f;
      arg = node;
    }
#pragma unroll
    for (int off = 32; off; off >>= 1) {
      float mo = __shfl_xor(m, off);
      float so = __shfl_xor(ssum, off);
      int ao = __shfl_xor(arg, off);
      combine(m, ssum, arg, mo, so, ao);
    }
    if (lane == 0) { redM[wave] = m; redS[wave] = ssum; redI[wave] = arg; }
    __syncthreads();  // B6: reductions ready

    // ---- pick action, update compacted list
    if (tid == 0) {
      float M = redM[0], S = redS[0];
      int A = redI[0];
      for (int w = 1; w < 16; ++w) combine(M, S, A, redM[w], redS[w], redI[w]);
      // chosen logit == M, so log_p[act] = M - (M + log S) = -log S
      total_s += -logf(S);
      cur_s = A;
      int jp = pos[A];
      int lastn = rem[R - 1];
      rem[jp] = lastn;
      pos[lastn] = jp;
      R_s = R - 1;
    }
    __syncthreads();  // B7: state updated
  }
  if (tid == 0) out[b] = total_s;
}

// ---------------------------------------------------------------------------
extern "C" void kernel_launch(void* const* d_in, const int* in_sizes, int n_in,
                              void* d_out, int out_size, void* d_ws,
                              size_t ws_size, hipStream_t stream) {
  const float* ne = (const float*)d_in[0];
  const float* ge = (const float*)d_in[1];
  const float* Wqkv = (const float*)d_in[2];
  const float* bqkv = (const float*)d_in[3];
  const float* Wfix = (const float*)d_in[4];
  const float* bfix = (const float*)d_in[5];
  const float* Wstep = (const float*)d_in[6];
  const float* bstep = (const float*)d_in[7];
  const float* Wmlp = (const float*)d_in[8];
  const float* bmlp = (const float*)d_in[9];
  float* out = (float*)d_out;

  size_t nkv = (size_t)kB * kN * kE;
  __half* kh = (__half*)d_ws;
  __half* vh = kh + nkv;
  __half* lkh = vh + nkv;
  float* qbase = (float*)(lkh + nkv);

  qkv_kernel<<<dim3(kB, (kN + 15) / 16), 384, 0, stream>>>(ne, Wqkv, bqkv, kh,
                                                           vh, lkh);
  qbase_kernel<<<kB, kE, 0, stream>>>(ne, ge, Wfix, bfix, Wstep, bstep, qbase);
  rollout_kernel<<<kB, 1024, 0, stream>>>(ne, Wstep, Wmlp, bmlp, kh, vh, lkh,
                                          qbase, out);
}

// Round 4
// 25957.916 us; speedup vs baseline: 1.0171x; 1.0171x over previous
//
#include <hip/hip_runtime.h>
#include <hip/hip_fp16.h>

constexpr int kB = 128;
constexpr int kN = 1000;
constexpr int kE = 128;
constexpr int kH = 8;
constexpr float kFP8Scale = 64.f;           // fp8 values stored as v*64
constexpr float kQKScale = 0.25f / 64.f;    // 1/sqrt(16) folded with 1/64
constexpr int kPStride = 9;                 // padded p row stride (floats)

typedef _Float16 h2 __attribute__((ext_vector_type(2)));
typedef float f2 __attribute__((ext_vector_type(2)));

__device__ __forceinline__ h2 pkrtz(float a, float b) {
  return __builtin_bit_cast(h2, __builtin_amdgcn_cvt_pkrtz(a, b));
}

// dot of 4 fp8 elems (packed in u, stored as value*64) against 4 f16 elems.
__device__ __forceinline__ float dotq(unsigned u, h2 qa, h2 qb_, float s) {
  f2 lo = __builtin_amdgcn_cvt_pk_f32_fp8(u, false);  // bytes 0,1
  f2 hi = __builtin_amdgcn_cvt_pk_f32_fp8(u, true);   // bytes 2,3
  h2 l16 = pkrtz(lo.x, lo.y);
  h2 h16 = pkrtz(hi.x, hi.y);
  s = __builtin_amdgcn_fdot2(l16, qa, s, false);
  s = __builtin_amdgcn_fdot2(h16, qb_, s, false);
  return s;
}
// 16-elem fp8 dot (one uint4) against 16 f16 elems (8 h2 at q8).
__device__ __forceinline__ float dot16(uint4 t, const h2* q8, float s) {
  s = dotq(t.x, q8[0], q8[1], s);
  s = dotq(t.y, q8[2], q8[3], s);
  s = dotq(t.z, q8[4], q8[5], s);
  s = dotq(t.w, q8[6], q8[7], s);
  return s;
}

__device__ __forceinline__ float fast_tanh(float x) {
  float t = __expf(2.f * x);
  return 1.f - 2.f / (t + 1.f);
}

__device__ __forceinline__ unsigned char enc_fp8(float v) {
  unsigned p = __builtin_amdgcn_cvt_pk_fp8_f32(v, v, 0, false);
  return (unsigned char)(p & 0xFF);
}

// online-softmax / argmax combine; tie -> smaller node id (jnp.argmax).
__device__ __forceinline__ void combine(float& m, float& s, int& a,
                                        float mo, float so, int ao) {
  bool take = (mo > m) || (mo == m && ao < a);
  float mw = take ? mo : m;
  float ml = take ? m : mo;
  float sw = take ? so : s;
  float sl = take ? s : so;
  s = sw + sl * __expf(ml - mw);
  m = mw;
  a = take ? ao : a;
}

// ---------------------------------------------------------------------------
// Kernel A: qkv projection -> fp8 (value*64) k / v / logit_k.
// ---------------------------------------------------------------------------
__global__ __launch_bounds__(384) void qkv_kernel(
    const float* __restrict__ ne, const float* __restrict__ Wqkv,
    const float* __restrict__ bqkv, unsigned char* __restrict__ kq,
    unsigned char* __restrict__ vq, unsigned char* __restrict__ lkq) {
  __shared__ float rows[16 * kE];
  int b = blockIdx.x;
  int n0 = blockIdx.y * 16;
  int ntile = min(16, kN - n0);
  int tid = threadIdx.x;

  for (int idx = tid; idx < ntile * kE; idx += 384)
    rows[idx] = ne[(b * kN + n0) * kE + idx];
  __syncthreads();

  int j = tid;  // 0..383
  float acc[16];
#pragma unroll
  for (int r = 0; r < 16; ++r) acc[r] = 0.f;
  for (int i = 0; i < kE; ++i) {
    float w = Wqkv[i * (3 * kE) + j];
#pragma unroll
    for (int r = 0; r < 16; ++r) acc[r] += rows[r * kE + i] * w;
  }
  float bias = bqkv[j];
  unsigned char* dst;
  int col;
  if (j < kE) { dst = kq; col = j; }
  else if (j < 2 * kE) { dst = vq; col = j - kE; }
  else { dst = lkq; col = j - 2 * kE; }
  for (int r = 0; r < ntile; ++r)
    dst[(size_t)(b * kN + n0 + r) * kE + col] =
        enc_fp8((acc[r] + bias) * kFP8Scale);
}

// ---------------------------------------------------------------------------
// Kernel B: qbase[b] = ge@Wfix + bfix + first@Wstep_top + bstep  (fp32)
// ---------------------------------------------------------------------------
__global__ __launch_bounds__(128) void qbase_kernel(
    const float* __restrict__ ne, const float* __restrict__ ge,
    const float* __restrict__ Wfix, const float* __restrict__ bfix,
    const float* __restrict__ Wstep, const float* __restrict__ bstep,
    float* __restrict__ qbase) {
  __shared__ float g[kE], f[kE];
  int b = blockIdx.x, e = threadIdx.x;
  g[e] = ge[b * kE + e];
  f[e] = ne[(size_t)b * kN * kE + e];  // node 0
  __syncthreads();
  float acc = bfix[e] + bstep[e];
  for (int i = 0; i < kE; ++i)
    acc += g[i] * Wfix[i * kE + e] + f[i] * Wstep[i * kE + e];
  qbase[b * kE + e] = acc;
}

// ---------------------------------------------------------------------------
// Kernel C: 999-step rollout, one 1024-thread block per batch element.
// fp8 k/v/lk gathers (1 line/row), register-resident matvec weights,
// k/lk row prefetch across barriers.
// ---------------------------------------------------------------------------
__global__ __launch_bounds__(1024) void rollout_kernel(
    const float* __restrict__ ne, const float* __restrict__ Wstep,
    const float* __restrict__ Wmlp, const float* __restrict__ bmlp,
    const unsigned char* __restrict__ kq, const unsigned char* __restrict__ vq,
    const unsigned char* __restrict__ lkq, const float* __restrict__ qbase,
    float* __restrict__ out) {
  __shared__ float p[kN * kPStride];   // exp(scores), [j*9+h], 36 KB
  __shared__ int rem[kN];              // live node ids
  __shared__ int pos[kN];              // node id -> position in rem
  __shared__ float parts[32 * kE];     // ctx half-wave partials, 16 KB
  __shared__ float qb[kE];
  __shared__ float bm[kE];
  __shared__ float ctx[kE];
  __shared__ __align__(16) __half qh[kE];
  __shared__ __align__(16) __half xh[kE];
  __shared__ float redSum[16][kH];
  __shared__ float redM[16], redS[16];
  __shared__ int redI[16];
  __shared__ int cur_s, R_s;
  __shared__ float total_s;

  int b = blockIdx.x;
  int tid = threadIdx.x;
  int lane = tid & 63;
  int wave = tid >> 6;
  int e8 = tid >> 3;  // matvec: output element
  int c8 = tid & 7;   // matvec: i-chunk (16 i's)

  const float* neb = ne + (size_t)b * kN * kE;
  const unsigned char* kqb = kq + (size_t)b * kN * kE;
  const unsigned char* vqb = vq + (size_t)b * kN * kE;
  const unsigned char* lqb = lkq + (size_t)b * kN * kE;

  // ---- per-thread register-resident weight columns (loaded once)
  const float* Wbot = Wstep + kE * kE;
  float wq[16], wm[16];
#pragma unroll
  for (int i = 0; i < 16; ++i) {
    wq[i] = Wbot[(c8 * 16 + i) * kE + e8];
    wm[i] = Wmlp[(c8 * 16 + i) * kE + e8];
  }

  for (int i = tid; i < kN - 1; i += 1024) { rem[i] = i + 1; pos[i + 1] = i; }
  if (tid < kE) { qb[tid] = qbase[b * kE + tid]; bm[tid] = bmlp[tid]; }
  if (tid == 0) { cur_s = 0; R_s = kN - 1; total_s = 0.f; }
  __syncthreads();

  for (int step = 0; step < kN - 1; ++step) {
    int R = R_s;
    int cur = cur_s;

    // ---- prefetch this thread's k row (fp8, 128B = 8 uint4)
    int node = -1;
    uint4 kr[8];
    if (tid < R) {
      node = rem[tid];
      const uint4* kp = (const uint4*)(kqb + (size_t)node * kE);
#pragma unroll
      for (int g = 0; g < 8; ++g) kr[g] = kp[g];
    }

    // ---- q = qb + ne[cur] @ Wbot (register weights, shuffle-reduce c8)
    {
      const float4* row4 = (const float4*)(neb + (size_t)cur * kE) + c8 * 4;
      float acc = 0.f;
#pragma unroll
      for (int qq = 0; qq < 4; ++qq) {
        float4 r = row4[qq];
        acc += r.x * wq[4 * qq + 0] + r.y * wq[4 * qq + 1] +
               r.z * wq[4 * qq + 2] + r.w * wq[4 * qq + 3];
      }
      acc += __shfl_xor(acc, 1);
      acc += __shfl_xor(acc, 2);
      acc += __shfl_xor(acc, 4);
      if (c8 == 0) qh[e8] = __float2half(qb[e8] + acc);
    }
    __syncthreads();  // B1: qh ready

    // ---- scores + exp (k rows already in registers)
    float hv[kH];
#pragma unroll
    for (int h = 0; h < kH; ++h) hv[h] = 0.f;
    if (tid < R) {
      const h2* q2 = (const h2*)qh;
#pragma unroll
      for (int h = 0; h < kH; ++h) {
        float s = dot16(kr[h], q2 + 8 * h, 0.f);
        hv[h] = __expf(s * kQKScale);  // scores tiny: no max-subtract
      }
      float* prow = p + tid * kPStride;
#pragma unroll
      for (int h = 0; h < kH; ++h) prow[h] = hv[h];
    }
    // ---- prefetch this thread's logit_k row (consumed 3 phases later)
    uint4 lkr[8];
    if (tid < R) {
      const uint4* lp = (const uint4*)(lqb + (size_t)node * kE);
#pragma unroll
      for (int g = 0; g < 8; ++g) lkr[g] = lp[g];
    }
#pragma unroll
    for (int h = 0; h < kH; ++h) {
      float v = hv[h];
#pragma unroll
      for (int off = 32; off; off >>= 1) v += __shfl_xor(v, off);
      if (lane == 0) redSum[wave][h] = v;
    }
    __syncthreads();  // B2: p, redSum ready

    // ---- ctx partials: half-wave per node, fp8 v (1 line/row)
    {
      int hw = lane >> 5;   // half-wave
      int idx = lane & 31;  // uint index within 128B row
      int h = idx >> 2;     // head of elems 4idx..4idx+3
      float a0 = 0.f, a1 = 0.f, a2 = 0.f, a3 = 0.f;
#pragma unroll 2
      for (int j = 2 * wave + hw; j < R; j += 32) {
        int nj = rem[j];
        unsigned u = ((const unsigned*)(vqb + (size_t)nj * kE))[idx];
        float w_ = p[j * kPStride + h];
        f2 lo = __builtin_amdgcn_cvt_pk_f32_fp8(u, false);
        f2 hi = __builtin_amdgcn_cvt_pk_f32_fp8(u, true);
        a0 += w_ * lo.x;
        a1 += w_ * lo.y;
        a2 += w_ * hi.x;
        a3 += w_ * hi.y;
      }
      ((float4*)(parts + (wave * 2 + hw) * kE))[idx] =
          make_float4(a0, a1, a2, a3);
    }
    __syncthreads();  // B3: parts ready

    // ---- ctx combine + softmax normalize (+ undo fp8 scale)
    if (tid < kE) {
      int h = tid >> 4;
      float den = 0.f, s = 0.f;
#pragma unroll
      for (int w = 0; w < 16; ++w) den += redSum[w][h];
#pragma unroll
      for (int w = 0; w < 32; ++w) s += parts[w * kE + tid];
      ctx[tid] = s / (den * kFP8Scale);
    }
    __syncthreads();  // B4: ctx ready

    // ---- x = bm + ctx @ Wmlp (register weights)
    {
      float acc = 0.f;
#pragma unroll
      for (int i = 0; i < 16; ++i) acc += ctx[c8 * 16 + i] * wm[i];
      acc += __shfl_xor(acc, 1);
      acc += __shfl_xor(acc, 2);
      acc += __shfl_xor(acc, 4);
      if (c8 == 0) xh[e8] = __float2half(bm[e8] + acc);
    }
    __syncthreads();  // B5: xh ready

    // ---- logits (lk rows already in registers) + online log-softmax/argmax
    float m = -1e30f, ssum = 0.f;
    int arg = 0x7fffffff;
    if (tid < R) {
      const h2* x2 = (const h2*)xh;
      float s = 0.f;
#pragma unroll
      for (int g = 0; g < 8; ++g) s = dot16(lkr[g], x2 + 8 * g, s);
      m = fast_tanh(s * kQKScale) * 10.f;
      ssum = 1.f;
      arg = node;
    }
#pragma unroll
    for (int off = 32; off; off >>= 1) {
      float mo = __shfl_xor(m, off);
      float so = __shfl_xor(ssum, off);
      int ao = __shfl_xor(arg, off);
      combine(m, ssum, arg, mo, so, ao);
    }
    if (lane == 0) { redM[wave] = m; redS[wave] = ssum; redI[wave] = arg; }
    __syncthreads();  // B6: reductions ready

    // ---- pick action, swap-remove from live list
    if (tid == 0) {
      float M = redM[0], S = redS[0];
      int A = redI[0];
      for (int w = 1; w < 16; ++w) combine(M, S, A, redM[w], redS[w], redI[w]);
      total_s += -logf(S);  // chosen logit == M => log_p[act] = -log S
      cur_s = A;
      int jp = pos[A];
      int lastn = rem[R - 1];
      rem[jp] = lastn;
      pos[lastn] = jp;
      R_s = R - 1;
    }
    __syncthreads();  // B7: state updated
  }
  if (tid == 0) out[b] = total_s;
}

// ---------------------------------------------------------------------------
extern "C" void kernel_launch(void* const* d_in, const int* in_sizes, int n_in,
                              void* d_out, int out_size, void* d_ws,
                              size_t ws_size, hipStream_t stream) {
  const float* ne = (const float*)d_in[0];
  const float* ge = (const float*)d_in[1];
  const float* Wqkv = (const float*)d_in[2];
  const float* bqkv = (const float*)d_in[3];
  const float* Wfix = (const float*)d_in[4];
  const float* bfix = (const float*)d_in[5];
  const float* Wstep = (const float*)d_in[6];
  const float* bstep = (const float*)d_in[7];
  const float* Wmlp = (const float*)d_in[8];
  const float* bmlp = (const float*)d_in[9];
  float* out = (float*)d_out;

  size_t nkv = (size_t)kB * kN * kE;  // bytes per fp8 tensor
  unsigned char* kq = (unsigned char*)d_ws;
  unsigned char* vq = kq + nkv;
  unsigned char* lkq = vq + nkv;
  float* qbase = (float*)(lkq + nkv);  // 16B-aligned offset

  qkv_kernel<<<dim3(kB, (kN + 15) / 16), 384, 0, stream>>>(ne, Wqkv, bqkv, kq,
                                                           vq, lkq);
  qbase_kernel<<<kB, kE, 0, stream>>>(ne, ge, Wfix, bfix, Wstep, bstep, qbase);
  rollout_kernel<<<kB, 1024, 0, stream>>>(ne, Wstep, Wmlp, bmlp, kq, vq, lkq,
                                          qbase, out);
}

// Round 5
// 21589.627 us; speedup vs baseline: 1.2229x; 1.2023x over previous
//
#include <hip/hip_runtime.h>
#include <hip/hip_fp16.h>

constexpr int kB = 128;
constexpr int kN = 1000;
constexpr int kE = 128;
constexpr int kH = 8;
constexpr float kFP8Scale = 64.f;         // fp8 values stored as v*64
constexpr float kQKScale = 0.25f / 64.f;  // 1/sqrt(16) folded with 1/64
constexpr int kPStride = 9;               // padded p row stride (floats)

typedef _Float16 h2 __attribute__((ext_vector_type(2)));
typedef float f2 __attribute__((ext_vector_type(2)));

__device__ __forceinline__ h2 pkrtz(float a, float b) {
  return __builtin_bit_cast(h2, __builtin_amdgcn_cvt_pkrtz(a, b));
}

// dot of 4 fp8 elems (packed in u, stored as value*64) against 4 f16 elems.
__device__ __forceinline__ float dotq(unsigned u, h2 qa, h2 qb_, float s) {
  f2 lo = __builtin_amdgcn_cvt_pk_f32_fp8(u, false);  // bytes 0,1
  f2 hi = __builtin_amdgcn_cvt_pk_f32_fp8(u, true);   // bytes 2,3
  h2 l16 = pkrtz(lo.x, lo.y);
  h2 h16 = pkrtz(hi.x, hi.y);
  s = __builtin_amdgcn_fdot2(l16, qa, s, false);
  s = __builtin_amdgcn_fdot2(h16, qb_, s, false);
  return s;
}
// 16-elem fp8 dot (one uint4) against 16 f16 elems (8 h2 at q8).
__device__ __forceinline__ float dot16(uint4 t, const h2* q8, float s) {
  s = dotq(t.x, q8[0], q8[1], s);
  s = dotq(t.y, q8[2], q8[3], s);
  s = dotq(t.z, q8[4], q8[5], s);
  s = dotq(t.w, q8[6], q8[7], s);
  return s;
}

__device__ __forceinline__ float fast_tanh(float x) {
  float t = __expf(2.f * x);
  return 1.f - 2.f / (t + 1.f);
}

__device__ __forceinline__ unsigned char enc_fp8(float v) {
  unsigned p = __builtin_amdgcn_cvt_pk_fp8_f32(v, v, 0, false);
  return (unsigned char)(p & 0xFF);
}

#define PIN4(q)                                                       \
  asm volatile("" : "+v"((q).x), "+v"((q).y), "+v"((q).z), "+v"((q).w))

// online-softmax / argmax combine; tie -> smaller node id (jnp.argmax).
__device__ __forceinline__ void combine(float& m, float& s, int& a,
                                        float mo, float so, int ao) {
  bool take = (mo > m) || (mo == m && ao < a);
  float mw = take ? mo : m;
  float ml = take ? m : mo;
  float sw = take ? so : s;
  float sl = take ? s : so;
  s = sw + sl * __expf(ml - mw);
  m = mw;
  a = take ? ao : a;
}

// ---------------------------------------------------------------------------
// Kernel A: qkv projection -> fp8 (value*64) k / v / logit_k.
// ---------------------------------------------------------------------------
__global__ __launch_bounds__(384) void qkv_kernel(
    const float* __restrict__ ne, const float* __restrict__ Wqkv,
    const float* __restrict__ bqkv, unsigned char* __restrict__ kq,
    unsigned char* __restrict__ vq, unsigned char* __restrict__ lkq) {
  __shared__ float rows[16 * kE];
  int b = blockIdx.x;
  int n0 = blockIdx.y * 16;
  int ntile = min(16, kN - n0);
  int tid = threadIdx.x;

  for (int idx = tid; idx < ntile * kE; idx += 384)
    rows[idx] = ne[(b * kN + n0) * kE + idx];
  __syncthreads();

  int j = tid;  // 0..383
  float acc[16];
#pragma unroll
  for (int r = 0; r < 16; ++r) acc[r] = 0.f;
  for (int i = 0; i < kE; ++i) {
    float w = Wqkv[i * (3 * kE) + j];
#pragma unroll
    for (int r = 0; r < 16; ++r) acc[r] += rows[r * kE + i] * w;
  }
  float bias = bqkv[j];
  unsigned char* dst;
  int col;
  if (j < kE) { dst = kq; col = j; }
  else if (j < 2 * kE) { dst = vq; col = j - kE; }
  else { dst = lkq; col = j - 2 * kE; }
  for (int r = 0; r < ntile; ++r)
    dst[(size_t)(b * kN + n0 + r) * kE + col] =
        enc_fp8((acc[r] + bias) * kFP8Scale);
}

// ---------------------------------------------------------------------------
// Kernel B: qbase[b] = ge@Wfix + bfix + first@Wstep_top + bstep  (fp32)
// ---------------------------------------------------------------------------
__global__ __launch_bounds__(128) void qbase_kernel(
    const float* __restrict__ ne, const float* __restrict__ ge,
    const float* __restrict__ Wfix, const float* __restrict__ bfix,
    const float* __restrict__ Wstep, const float* __restrict__ bstep,
    float* __restrict__ qbase) {
  __shared__ float g[kE], f[kE];
  int b = blockIdx.x, e = threadIdx.x;
  g[e] = ge[b * kE + e];
  f[e] = ne[(size_t)b * kN * kE + e];  // node 0
  __syncthreads();
  float acc = bfix[e] + bstep[e];
  for (int i = 0; i < kE; ++i)
    acc += g[i] * Wfix[i * kE + e] + f[i] * Wstep[i * kE + e];
  qbase[b * kE + e] = acc;
}

// ---------------------------------------------------------------------------
// Kernel B2: qstep[b,n] = (qbase[b] + ne[b,n] @ Wbot) * kQKScale, f16.
// Removes the per-step q matvec from the rollout critical path.
// ---------------------------------------------------------------------------
__global__ __launch_bounds__(128) void qstep_kernel(
    const float* __restrict__ ne, const float* __restrict__ Wstep,
    const float* __restrict__ qbase, __half* __restrict__ qstep) {
  __shared__ float rows[8 * kE];
  int b = blockIdx.x;
  int n0 = blockIdx.y * 8;
  int tid = threadIdx.x;
  const float* Wbot = Wstep + kE * kE;

  for (int idx = tid; idx < 8 * kE; idx += 128)
    rows[idx] = ne[((size_t)b * kN + n0) * kE + idx];
  __syncthreads();

  float acc[8];
#pragma unroll
  for (int r = 0; r < 8; ++r) acc[r] = 0.f;
  for (int i = 0; i < kE; ++i) {
    float w = Wbot[i * kE + tid];
#pragma unroll
    for (int r = 0; r < 8; ++r) acc[r] += rows[r * kE + i] * w;
  }
  float qb = qbase[b * kE + tid];
#pragma unroll
  for (int r = 0; r < 8; ++r)
    qstep[((size_t)b * kN + n0 + r) * kE + tid] =
        __float2half((qb + acc[r]) * kQKScale);
}

// ---------------------------------------------------------------------------
// Kernel C: 999-step rollout, one 1024-thread block per batch element.
// Pinned k/lk row prefetch (drained collectively at B1), batched v gather.
// ---------------------------------------------------------------------------
__global__ __launch_bounds__(1024) void rollout_kernel(
    const float* __restrict__ Wmlp, const float* __restrict__ bmlp,
    const unsigned char* __restrict__ kq, const unsigned char* __restrict__ vq,
    const unsigned char* __restrict__ lkq, const __half* __restrict__ qstep,
    float* __restrict__ out) {
  __shared__ float p[kN * kPStride];   // exp(scores), [j*9+h], 36 KB
  __shared__ int rem[kN];              // live node ids
  __shared__ int pos[kN];              // node id -> position in rem
  __shared__ float parts[32 * kE];     // ctx half-wave partials, 16 KB
  __shared__ float bm[kE];
  __shared__ float ctx[kE];
  __shared__ __align__(16) __half qh[kE];
  __shared__ __align__(16) __half xh[kE];
  __shared__ float redSum[16][kH];
  __shared__ float redM[16], redS[16];
  __shared__ int redI[16];
  __shared__ int cur_s, R_s;
  __shared__ float total_s;

  int b = blockIdx.x;
  int tid = threadIdx.x;
  int lane = tid & 63;
  int wave = tid >> 6;
  int e8 = tid >> 3;  // x matvec: output element
  int c8 = tid & 7;   // x matvec: i-chunk (16 i's)

  const unsigned char* kqb = kq + (size_t)b * kN * kE;
  const unsigned char* vqb = vq + (size_t)b * kN * kE;
  const unsigned char* lqb = lkq + (size_t)b * kN * kE;
  const __half* qsb = qstep + (size_t)b * kN * kE;

  // x-matvec weight column, register resident
  float wm[16];
#pragma unroll
  for (int i = 0; i < 16; ++i) wm[i] = Wmlp[(c8 * 16 + i) * kE + e8];

  for (int i = tid; i < kN - 1; i += 1024) { rem[i] = i + 1; pos[i + 1] = i; }
  if (tid < kE) bm[tid] = bmlp[tid];
  if (tid == 0) { cur_s = 0; R_s = kN - 1; total_s = 0.f; }
  __syncthreads();

  for (int step = 0; step < kN - 1; ++step) {
    int R = R_s;
    int cur = cur_s;

    // ---- issue k row + lk row prefetch for this thread's live node.
    // Pinned so the compiler cannot sink them past B1; the barrier's
    // vmcnt(0) drain collects ALL ~2R lines at once.
    int node = -1;
    uint4 kr[8], lkr[8];
    if (tid < R) {
      node = rem[tid];
      const uint4* kp = (const uint4*)(kqb + (size_t)node * kE);
      const uint4* lp = (const uint4*)(lqb + (size_t)node * kE);
#pragma unroll
      for (int g = 0; g < 8; ++g) kr[g] = kp[g];
#pragma unroll
      for (int g = 0; g < 8; ++g) lkr[g] = lp[g];
    }
    // ---- q row (precomputed, pre-scaled)
    if (tid < kE) qh[tid] = qsb[(size_t)cur * kE + tid];
    if (tid < R) {
#pragma unroll
      for (int g = 0; g < 8; ++g) { PIN4(kr[g]); PIN4(lkr[g]); }
    }
    __syncthreads();  // B1: qh ready, prefetches drained

    // ---- scores + exp (k rows in registers; q pre-scaled)
    float hv[kH];
#pragma unroll
    for (int h = 0; h < kH; ++h) hv[h] = 0.f;
    if (tid < R) {
      const h2* q2 = (const h2*)qh;
#pragma unroll
      for (int h = 0; h < kH; ++h) {
        float s = dot16(kr[h], q2 + 8 * h, 0.f);
        hv[h] = __expf(s);  // scores tiny: no max-subtract
      }
      float* prow = p + tid * kPStride;
#pragma unroll
      for (int h = 0; h < kH; ++h) prow[h] = hv[h];
    }
#pragma unroll
    for (int h = 0; h < kH; ++h) {
      float v = hv[h];
#pragma unroll
      for (int off = 32; off; off >>= 1) v += __shfl_xor(v, off);
      if (lane == 0) redSum[wave][h] = v;
    }
    __syncthreads();  // B2: p, redSum ready

    // ---- ctx partials: half-wave per node, batched gather (MLP=8)
    {
      int hw = lane >> 5;   // half-wave
      int idx = lane & 31;  // uint index within 128B row
      int h = idx >> 2;     // head of elems 4idx..4idx+3
      float a0 = 0.f, a1 = 0.f, a2 = 0.f, a3 = 0.f;
      int base = 2 * wave + hw;  // 0..31
      for (int j0 = base; j0 < R; j0 += 256) {
        unsigned u[8];
        float pw[8];
#pragma unroll
        for (int t = 0; t < 8; ++t) {
          int jj = j0 + t * 32;
          if (jj < R) {
            int nj = rem[jj];
            u[t] = ((const unsigned*)(vqb + (size_t)nj * kE))[idx];
            pw[t] = p[jj * kPStride + h];
          }
        }
#pragma unroll
        for (int t = 0; t < 8; ++t) {
          int jj = j0 + t * 32;
          if (jj < R) {
            f2 lo = __builtin_amdgcn_cvt_pk_f32_fp8(u[t], false);
            f2 hi = __builtin_amdgcn_cvt_pk_f32_fp8(u[t], true);
            a0 += pw[t] * lo.x;
            a1 += pw[t] * lo.y;
            a2 += pw[t] * hi.x;
            a3 += pw[t] * hi.y;
          }
        }
      }
      ((float4*)(parts + (wave * 2 + hw) * kE))[idx] =
          make_float4(a0, a1, a2, a3);
    }
    __syncthreads();  // B3: parts ready

    // ---- ctx combine + softmax normalize (+ undo fp8 scale)
    if (tid < kE) {
      int h = tid >> 4;
      float den = 0.f, s = 0.f;
#pragma unroll
      for (int w = 0; w < 16; ++w) den += redSum[w][h];
#pragma unroll
      for (int w = 0; w < 32; ++w) s += parts[w * kE + tid];
      ctx[tid] = s / (den * kFP8Scale);
    }
    __syncthreads();  // B4: ctx ready

    // ---- x = (bm + ctx @ Wmlp) * kQKScale (register weights)
    {
      float acc = 0.f;
#pragma unroll
      for (int i = 0; i < 16; ++i) acc += ctx[c8 * 16 + i] * wm[i];
      acc += __shfl_xor(acc, 1);
      acc += __shfl_xor(acc, 2);
      acc += __shfl_xor(acc, 4);
      if (c8 == 0) xh[e8] = __float2half((bm[e8] + acc) * kQKScale);
    }
    __syncthreads();  // B5: xh ready

    // ---- logits (lk rows in registers) + online log-softmax/argmax
    float m = -1e30f, ssum = 0.f;
    int arg = 0x7fffffff;
    if (tid < R) {
      const h2* x2 = (const h2*)xh;
      float s = 0.f;
#pragma unroll
      for (int g = 0; g < 8; ++g) s = dot16(lkr[g], x2 + 8 * g, s);
      m = fast_tanh(s) * 10.f;
      ssum = 1.f;
      arg = node;
    }
#pragma unroll
    for (int off = 32; off; off >>= 1) {
      float mo = __shfl_xor(m, off);
      float so = __shfl_xor(ssum, off);
      int ao = __shfl_xor(arg, off);
      combine(m, ssum, arg, mo, so, ao);
    }
    if (lane == 0) { redM[wave] = m; redS[wave] = ssum; redI[wave] = arg; }
    __syncthreads();  // B6: reductions ready

    // ---- pick action, swap-remove from live list
    if (tid == 0) {
      float M = redM[0], S = redS[0];
      int A = redI[0];
      for (int w = 1; w < 16; ++w) combine(M, S, A, redM[w], redS[w], redI[w]);
      total_s += -logf(S);  // chosen logit == M => log_p[act] = -log S
      cur_s = A;
      int jp = pos[A];
      int lastn = rem[R - 1];
      rem[jp] = lastn;
      pos[lastn] = jp;
      R_s = R - 1;
    }
    __syncthreads();  // B7: state updated
  }
  if (tid == 0) out[b] = total_s;
}

// ---------------------------------------------------------------------------
extern "C" void kernel_launch(void* const* d_in, const int* in_sizes, int n_in,
                              void* d_out, int out_size, void* d_ws,
                              size_t ws_size, hipStream_t stream) {
  const float* ne = (const float*)d_in[0];
  const float* ge = (const float*)d_in[1];
  const float* Wqkv = (const float*)d_in[2];
  const float* bqkv = (const float*)d_in[3];
  const float* Wfix = (const float*)d_in[4];
  const float* bfix = (const float*)d_in[5];
  const float* Wstep = (const float*)d_in[6];
  const float* bstep = (const float*)d_in[7];
  const float* Wmlp = (const float*)d_in[8];
  const float* bmlp = (const float*)d_in[9];
  float* out = (float*)d_out;

  size_t nkv = (size_t)kB * kN * kE;  // bytes per fp8 tensor
  unsigned char* kq = (unsigned char*)d_ws;
  unsigned char* vq = kq + nkv;
  unsigned char* lkq = vq + nkv;
  __half* qstep = (__half*)(lkq + nkv);      // 2*nkv bytes
  float* qbase = (float*)(qstep + nkv);      // 64 KB

  qkv_kernel<<<dim3(kB, (kN + 15) / 16), 384, 0, stream>>>(ne, Wqkv, bqkv, kq,
                                                           vq, lkq);
  qbase_kernel<<<kB, kE, 0, stream>>>(ne, ge, Wfix, bfix, Wstep, bstep, qbase);
  qstep_kernel<<<dim3(kB, kN / 8), 128, 0, stream>>>(ne, Wstep, qbase, qstep);
  rollout_kernel<<<kB, 1024, 0, stream>>>(Wmlp, bmlp, kq, vq, lkq, qstep, out);
}

// Round 6
// 14812.199 us; speedup vs baseline: 1.7825x; 1.4576x over previous
//
#include <hip/hip_runtime.h>
#include <hip/hip_fp16.h>

constexpr int kB = 128;
constexpr int kN = 1000;
constexpr int kE = 128;
constexpr int kH = 8;
constexpr float kFP8Scale = 64.f;         // fp8 values stored as v*64
constexpr float kQKScale = 0.25f / 64.f;  // 1/sqrt(16) folded with 1/64

typedef _Float16 h2 __attribute__((ext_vector_type(2)));
typedef float f2 __attribute__((ext_vector_type(2)));

__device__ __forceinline__ h2 pkrtz(float a, float b) {
  return __builtin_bit_cast(h2, __builtin_amdgcn_cvt_pkrtz(a, b));
}

// dot of 4 fp8 elems (packed in u, stored value*64) against 4 f16 elems.
__device__ __forceinline__ float dotq(unsigned u, h2 qa, h2 qb_, float s) {
  f2 lo = __builtin_amdgcn_cvt_pk_f32_fp8(u, false);
  f2 hi = __builtin_amdgcn_cvt_pk_f32_fp8(u, true);
  h2 l16 = pkrtz(lo.x, lo.y);
  h2 h16 = pkrtz(hi.x, hi.y);
  s = __builtin_amdgcn_fdot2(l16, qa, s, false);
  s = __builtin_amdgcn_fdot2(h16, qb_, s, false);
  return s;
}
// 16-elem fp8 dot (one uint4) against 16 f16 elems in q8[0..7].
__device__ __forceinline__ float dot16(uint4 tq, const h2* q8, float s) {
  s = dotq(tq.x, q8[0], q8[1], s);
  s = dotq(tq.y, q8[2], q8[3], s);
  s = dotq(tq.z, q8[4], q8[5], s);
  s = dotq(tq.w, q8[6], q8[7], s);
  return s;
}

__device__ __forceinline__ float fast_tanh(float x) {
  float t = __expf(2.f * x);
  return 1.f - 2.f / (t + 1.f);
}

__device__ __forceinline__ unsigned char enc_fp8(float v) {
  unsigned p = __builtin_amdgcn_cvt_pk_fp8_f32(v, v, 0, false);
  return (unsigned char)(p & 0xFF);
}

// online-softmax / argmax combine; tie -> smaller node id (jnp.argmax).
__device__ __forceinline__ void combine(float& m, float& s, int& a,
                                        float mo, float so, int ao) {
  bool take = (mo > m) || (mo == m && ao < a);
  float mw = take ? mo : m;
  float ml = take ? m : mo;
  float sw = take ? so : s;
  float sl = take ? s : so;
  s = sw + sl * __expf(ml - mw);
  m = mw;
  a = take ? ao : a;
}

// ---------------------------------------------------------------------------
// Kernel A: qkv projection -> fp8 (value*64) k / v / logit_k.
// ---------------------------------------------------------------------------
__global__ __launch_bounds__(384) void qkv_kernel(
    const float* __restrict__ ne, const float* __restrict__ Wqkv,
    const float* __restrict__ bqkv, unsigned char* __restrict__ kq,
    unsigned char* __restrict__ vq, unsigned char* __restrict__ lkq) {
  __shared__ float rows[16 * kE];
  int b = blockIdx.x;
  int n0 = blockIdx.y * 16;
  int ntile = min(16, kN - n0);
  int tid = threadIdx.x;

  for (int idx = tid; idx < ntile * kE; idx += 384)
    rows[idx] = ne[(b * kN + n0) * kE + idx];
  __syncthreads();

  int j = tid;  // 0..383
  float acc[16];
#pragma unroll
  for (int r = 0; r < 16; ++r) acc[r] = 0.f;
  for (int i = 0; i < kE; ++i) {
    float w = Wqkv[i * (3 * kE) + j];
#pragma unroll
    for (int r = 0; r < 16; ++r) acc[r] += rows[r * kE + i] * w;
  }
  float bias = bqkv[j];
  unsigned char* dst;
  int col;
  if (j < kE) { dst = kq; col = j; }
  else if (j < 2 * kE) { dst = vq; col = j - kE; }
  else { dst = lkq; col = j - 2 * kE; }
  for (int r = 0; r < ntile; ++r)
    dst[(size_t)(b * kN + n0 + r) * kE + col] =
        enc_fp8((acc[r] + bias) * kFP8Scale);
}

// ---------------------------------------------------------------------------
// Kernel B: qbase[b] = ge@Wfix + bfix + first@Wstep_top + bstep  (fp32)
// ---------------------------------------------------------------------------
__global__ __launch_bounds__(128) void qbase_kernel(
    const float* __restrict__ ne, const float* __restrict__ ge,
    const float* __restrict__ Wfix, const float* __restrict__ bfix,
    const float* __restrict__ Wstep, const float* __restrict__ bstep,
    float* __restrict__ qbase) {
  __shared__ float g[kE], f[kE];
  int b = blockIdx.x, e = threadIdx.x;
  g[e] = ge[b * kE + e];
  f[e] = ne[(size_t)b * kN * kE + e];  // node 0
  __syncthreads();
  float acc = bfix[e] + bstep[e];
  for (int i = 0; i < kE; ++i)
    acc += g[i] * Wfix[i * kE + e] + f[i] * Wstep[i * kE + e];
  qbase[b * kE + e] = acc;
}

// ---------------------------------------------------------------------------
// Kernel B2: qstep[b,n] = (qbase[b] + ne[b,n] @ Wbot) * kQKScale, f16.
// ---------------------------------------------------------------------------
__global__ __launch_bounds__(128) void qstep_kernel(
    const float* __restrict__ ne, const float* __restrict__ Wstep,
    const float* __restrict__ qbase, __half* __restrict__ qstep) {
  __shared__ float rows[8 * kE];
  int b = blockIdx.x;
  int n0 = blockIdx.y * 8;
  int tid = threadIdx.x;
  const float* Wbot = Wstep + kE * kE;

  for (int idx = tid; idx < 8 * kE; idx += 128)
    rows[idx] = ne[((size_t)b * kN + n0) * kE + idx];
  __syncthreads();

  float acc[8];
#pragma unroll
  for (int r = 0; r < 8; ++r) acc[r] = 0.f;
  for (int i = 0; i < kE; ++i) {
    float w = Wbot[i * kE + tid];
#pragma unroll
    for (int r = 0; r < 8; ++r) acc[r] += rows[r * kE + i] * w;
  }
  float qb = qbase[b * kE + tid];
#pragma unroll
  for (int r = 0; r < 8; ++r)
    qstep[((size_t)b * kN + n0 + r) * kE + tid] =
        __float2half((qb + acc[r]) * kQKScale);
}

// ---------------------------------------------------------------------------
// Kernel C: 999-step rollout, one 1024-thread block per batch element.
// 8 threads per node: thread t handles uint4 #t (= head t) of each row.
// Coalesced full-line gathers, no register row-arrays, no spills.
// ---------------------------------------------------------------------------
__global__ __launch_bounds__(1024) void rollout_kernel(
    const float* __restrict__ Wmlp, const float* __restrict__ bmlp,
    const unsigned char* __restrict__ kq, const unsigned char* __restrict__ vq,
    const unsigned char* __restrict__ lkq, const __half* __restrict__ qstep,
    float* __restrict__ out) {
  __shared__ float p[kN * kH];     // exp(scores), [j*8+h], 32 KB
  __shared__ int rem[kN];          // live node ids
  __shared__ int pos[kN];          // node id -> position in rem
  __shared__ float parts[32 * kE]; // ctx half-wave partials, 16 KB
  __shared__ float bm[kE];
  __shared__ float ctx[kE];
  __shared__ __align__(16) __half qh[kE];
  __shared__ __align__(16) __half xh[kE];
  __shared__ float redSum[16][kH];
  __shared__ float redM[16], redS[16];
  __shared__ int redI[16];
  __shared__ int cur_s, R_s;
  __shared__ float total_s;

  int b = blockIdx.x;
  int tid = threadIdx.x;
  int lane = tid & 63;
  int wave = tid >> 6;
  int g = tid >> 3;  // node-group 0..127
  int t = tid & 7;   // head / uint4 slot within row

  const unsigned char* kqb = kq + (size_t)b * kN * kE;
  const unsigned char* vqb = vq + (size_t)b * kN * kE;
  const unsigned char* lqb = lkq + (size_t)b * kN * kE;
  const __half* qsb = qstep + (size_t)b * kN * kE;

  // x-matvec weight column (output elem g, i-chunk t), register resident
  float wm[16];
#pragma unroll
  for (int i = 0; i < 16; ++i) wm[i] = Wmlp[(t * 16 + i) * kE + g];

  for (int i = tid; i < kN - 1; i += 1024) { rem[i] = i + 1; pos[i + 1] = i; }
  if (tid < kE) bm[tid] = bmlp[tid];
  if (tid == 0) { cur_s = 0; R_s = kN - 1; total_s = 0.f; }
  __syncthreads();

  for (int step = 0; step < kN - 1; ++step) {
    int R = R_s;

    // ---- q row (precomputed, pre-scaled f16)
    if (tid < kE) qh[tid] = qsb[(size_t)cur_s * kE + tid];
    __syncthreads();  // B1: qh ready

    // ---- scores + exp: group g, rounds r -> node rem[g+128r], head t
    float den = 0.f;
    {
      h2 q8[8];
#pragma unroll
      for (int i = 0; i < 8; ++i) q8[i] = ((const h2*)qh)[8 * t + i];
      int jn[8];
      uint4 ku[8];
#pragma unroll
      for (int r = 0; r < 8; ++r) {
        int j = g + 128 * r;
        jn[r] = (j < R) ? rem[j] : -1;
      }
#pragma unroll
      for (int r = 0; r < 8; ++r)
        if (jn[r] >= 0)
          ku[r] = ((const uint4*)(kqb + (size_t)jn[r] * kE))[t];
#pragma unroll
      for (int r = 0; r < 8; ++r) {
        if (jn[r] >= 0) {
          float s = dot16(ku[r], q8, 0.f);
          float hv = __expf(s);  // scores tiny: no max-subtract
          p[(g + 128 * r) * kH + t] = hv;
          den += hv;
        }
      }
    }
    den += __shfl_xor(den, 8);
    den += __shfl_xor(den, 16);
    den += __shfl_xor(den, 32);
    if (lane < kH) redSum[wave][lane] = den;  // lane==t for lanes 0..7
    __syncthreads();  // B2: p, redSum ready

    // ---- ctx partials: half-wave per node (one full line), batched
    {
      int hw = lane >> 5;   // half-wave
      int idx = lane & 31;  // uint index within 128B row
      int h = idx >> 2;     // head of elems 4idx..4idx+3
      float a0 = 0.f, a1 = 0.f, a2 = 0.f, a3 = 0.f;
      int base = 2 * wave + hw;  // 0..31
      for (int j0 = base; j0 < R; j0 += 256) {
        unsigned u[8];
        float pw[8];
#pragma unroll
        for (int q = 0; q < 8; ++q) {
          int jj = j0 + q * 32;
          if (jj < R) {
            int nj = rem[jj];
            u[q] = ((const unsigned*)(vqb + (size_t)nj * kE))[idx];
            pw[q] = p[jj * kH + h];
          }
        }
#pragma unroll
        for (int q = 0; q < 8; ++q) {
          int jj = j0 + q * 32;
          if (jj < R) {
            f2 lo = __builtin_amdgcn_cvt_pk_f32_fp8(u[q], false);
            f2 hi = __builtin_amdgcn_cvt_pk_f32_fp8(u[q], true);
            a0 += pw[q] * lo.x;
            a1 += pw[q] * lo.y;
            a2 += pw[q] * hi.x;
            a3 += pw[q] * hi.y;
          }
        }
      }
      ((float4*)(parts + (wave * 2 + hw) * kE))[idx] =
          make_float4(a0, a1, a2, a3);
    }
    __syncthreads();  // B3: parts ready

    // ---- ctx combine + softmax normalize (+ undo fp8 scale)
    if (tid < kE) {
      int h = tid >> 4;
      float d2 = 0.f, s = 0.f;
#pragma unroll
      for (int w = 0; w < 16; ++w) d2 += redSum[w][h];
#pragma unroll
      for (int w = 0; w < 32; ++w) s += parts[w * kE + tid];
      ctx[tid] = s / (d2 * kFP8Scale);
    }
    __syncthreads();  // B4: ctx ready

    // ---- x = (bm + ctx @ Wmlp) * kQKScale (register weights)
    {
      float acc = 0.f;
#pragma unroll
      for (int i = 0; i < 16; ++i) acc += ctx[t * 16 + i] * wm[i];
      acc += __shfl_xor(acc, 1);
      acc += __shfl_xor(acc, 2);
      acc += __shfl_xor(acc, 4);
      if (t == 0) xh[g] = __float2half((bm[g] + acc) * kQKScale);
    }
    __syncthreads();  // B5: xh ready

    // ---- logits: group per node, 3 intra-group shuffles for full dot
    float m = -1e30f, ssum = 0.f;
    int arg = 0x7fffffff;
    {
      h2 x8[8];
#pragma unroll
      for (int i = 0; i < 8; ++i) x8[i] = ((const h2*)xh)[8 * t + i];
      int jn[8];
      uint4 lu[8];
#pragma unroll
      for (int r = 0; r < 8; ++r) {
        int j = g + 128 * r;
        jn[r] = (j < R) ? rem[j] : -1;
      }
#pragma unroll
      for (int r = 0; r < 8; ++r)
        if (jn[r] >= 0)
          lu[r] = ((const uint4*)(lqb + (size_t)jn[r] * kE))[t];
#pragma unroll
      for (int r = 0; r < 8; ++r) {
        if (jn[r] >= 0) {
          float s = dot16(lu[r], x8, 0.f);
          s += __shfl_xor(s, 1);
          s += __shfl_xor(s, 2);
          s += __shfl_xor(s, 4);
          if (t == 0) {
            float l = fast_tanh(s) * 10.f;
            combine(m, ssum, arg, l, 1.f, jn[r]);
          }
        }
      }
    }
#pragma unroll
    for (int off = 32; off; off >>= 1) {
      float mo = __shfl_xor(m, off);
      float so = __shfl_xor(ssum, off);
      int ao = __shfl_xor(arg, off);
      combine(m, ssum, arg, mo, so, ao);
    }
    if (lane == 0) { redM[wave] = m; redS[wave] = ssum; redI[wave] = arg; }
    __syncthreads();  // B6: reductions ready

    // ---- pick action, swap-remove from live list
    if (tid == 0) {
      float M = redM[0], S = redS[0];
      int A = redI[0];
      for (int w = 1; w < 16; ++w) combine(M, S, A, redM[w], redS[w], redI[w]);
      total_s += -logf(S);  // chosen logit == M => log_p[act] = -log S
      cur_s = A;
      int jp = pos[A];
      int lastn = rem[R - 1];
      rem[jp] = lastn;
      pos[lastn] = jp;
      R_s = R - 1;
    }
    __syncthreads();  // B7: state updated
  }
  if (tid == 0) out[b] = total_s;
}

// ---------------------------------------------------------------------------
extern "C" void kernel_launch(void* const* d_in, const int* in_sizes, int n_in,
                              void* d_out, int out_size, void* d_ws,
                              size_t ws_size, hipStream_t stream) {
  const float* ne = (const float*)d_in[0];
  const float* ge = (const float*)d_in[1];
  const float* Wqkv = (const float*)d_in[2];
  const float* bqkv = (const float*)d_in[3];
  const float* Wfix = (const float*)d_in[4];
  const float* bfix = (const float*)d_in[5];
  const float* Wstep = (const float*)d_in[6];
  const float* bstep = (const float*)d_in[7];
  const float* Wmlp = (const float*)d_in[8];
  const float* bmlp = (const float*)d_in[9];
  float* out = (float*)d_out;

  size_t nkv = (size_t)kB * kN * kE;  // bytes per fp8 tensor
  unsigned char* kq = (unsigned char*)d_ws;
  unsigned char* vq = kq + nkv;
  unsigned char* lkq = vq + nkv;
  __half* qstep = (__half*)(lkq + nkv);  // 2*nkv bytes
  float* qbase = (float*)(qstep + nkv);  // 64 KB

  qkv_kernel<<<dim3(kB, (kN + 15) / 16), 384, 0, stream>>>(ne, Wqkv, bqkv, kq,
                                                           vq, lkq);
  qbase_kernel<<<kB, kE, 0, stream>>>(ne, ge, Wfix, bfix, Wstep, bstep, qbase);
  qstep_kernel<<<dim3(kB, kN / 8), 128, 0, stream>>>(ne, Wstep, qbase, qstep);
  rollout_kernel<<<kB, 1024, 0, stream>>>(Wmlp, bmlp, kq, vq, lkq, qstep, out);
}